// Round 5
// baseline (116.806 us; speedup 1.0000x reference)
//
#include <hip/hip_runtime.h>

#define B 4
#define LQ 512
#define LK 512
#define DQ 256
#define DC 256
#define H 128

// ws layout (floats):
//   Eq   [B*LQ][H]        = exp(2*(query@Wq^T + bq))            1 MB
//   EcT4 [B][H/4][LK][4]  = exp(4*(context@Wc^T + bc)), h-int.  1 MB
//   WqT4 [DQ/4][H][4]     transposed Wq                         128 KB
//   WcT4 [DC/4][H][4]     transposed Wc                         128 KB
//
// tanh(q + 2c) = 1 - 2/(e^{2q} e^{4c} + 1). The constant (bv + sum_h Wv)
// is softmax-shift-invariant and dropped. Paired reciprocals:
//   w0/A + w1/B = (w0*B + w1*A) / (A*B)  -> one rcp per two h.

__global__ __launch_bounds__(256) void ca_wt_kernel(
    const float* __restrict__ Wq, const float* __restrict__ Wc,
    float* __restrict__ WqT4, float* __restrict__ WcT4)
{
    const int blk = blockIdx.x;
    const bool is_q = blk < 128;
    const float* __restrict__ src = is_q ? Wq : Wc;
    float* __restrict__ dst = is_q ? WqT4 : WcT4;
    const int idx = ((is_q ? blk : blk - 128) << 8) + threadIdx.x; // h*DQ + d
    const int h = idx >> 8;
    const int d = idx & 255;
    dst[(((d >> 2) * H + h) << 2) + (d & 3)] = src[idx];
}

// ---------------------------------------------------------------------------
// Projection, LDS-free: 8 rows/block, 256 threads, grid 512 (2 blocks/CU).
// h = t&127; rg = t>>7 wave-uniform (readfirstlane) -> x rows s_load'ed.
// Each thread computes 4 rows (rg, rg+2, rg+4, rg+6) x 1 h.
// ---------------------------------------------------------------------------
__global__ __launch_bounds__(256, 4) void ca_proj_kernel(
    const float* __restrict__ query, const float* __restrict__ context,
    const float* __restrict__ WqT4, const float* __restrict__ WcT4,
    const float* __restrict__ bq, const float* __restrict__ bc,
    float* __restrict__ Eq, float* __restrict__ EcT4)
{
    const int t = threadIdx.x;
    const int blk = blockIdx.x;
    const bool is_q = blk < (B * LQ / 8);
    const int row0 = (is_q ? blk : blk - (B * LQ / 8)) * 8;
    const float* __restrict__ src = is_q ? query : context;
    const float4* __restrict__ w4 = (const float4*)(is_q ? WqT4 : WcT4);

    const int h = t & 127;
    const int rg = __builtin_amdgcn_readfirstlane(t >> 7); // wave-uniform 0/1

    const float* __restrict__ x0p = src + (size_t)(row0 + rg    ) * DQ;
    const float* __restrict__ x1p = src + (size_t)(row0 + rg + 2) * DQ;
    const float* __restrict__ x2p = src + (size_t)(row0 + rg + 4) * DQ;
    const float* __restrict__ x3p = src + (size_t)(row0 + rg + 6) * DQ;

    float acc0 = 0.f, acc1 = 0.f, acc2 = 0.f, acc3 = 0.f;
#pragma unroll 4
    for (int d4 = 0; d4 < DQ / 4; ++d4) {
        const float4 w  = w4[d4 * H + h];
        const float4 x0 = *(const float4*)(x0p + d4 * 4);
        const float4 x1 = *(const float4*)(x1p + d4 * 4);
        const float4 x2 = *(const float4*)(x2p + d4 * 4);
        const float4 x3 = *(const float4*)(x3p + d4 * 4);
        acc0 = fmaf(w.x, x0.x, acc0); acc0 = fmaf(w.y, x0.y, acc0);
        acc0 = fmaf(w.z, x0.z, acc0); acc0 = fmaf(w.w, x0.w, acc0);
        acc1 = fmaf(w.x, x1.x, acc1); acc1 = fmaf(w.y, x1.y, acc1);
        acc1 = fmaf(w.z, x1.z, acc1); acc1 = fmaf(w.w, x1.w, acc1);
        acc2 = fmaf(w.x, x2.x, acc2); acc2 = fmaf(w.y, x2.y, acc2);
        acc2 = fmaf(w.z, x2.z, acc2); acc2 = fmaf(w.w, x2.w, acc2);
        acc3 = fmaf(w.x, x3.x, acc3); acc3 = fmaf(w.y, x3.y, acc3);
        acc3 = fmaf(w.z, x3.z, acc3); acc3 = fmaf(w.w, x3.w, acc3);
    }

    const float bias = (is_q ? bq : bc)[h];
    if (is_q) {
        Eq[(size_t)(row0 + rg    ) * H + h] = __expf(2.f * (acc0 + bias));
        Eq[(size_t)(row0 + rg + 2) * H + h] = __expf(2.f * (acc1 + bias));
        Eq[(size_t)(row0 + rg + 4) * H + h] = __expf(2.f * (acc2 + bias));
        Eq[(size_t)(row0 + rg + 6) * H + h] = __expf(2.f * (acc3 + bias));
    } else {
        const int h4 = h >> 2, hl = h & 3;
        const float e0 = __expf(4.f * (acc0 + bias));
        const float e1 = __expf(4.f * (acc1 + bias));
        const float e2 = __expf(4.f * (acc2 + bias));
        const float e3 = __expf(4.f * (acc3 + bias));
        const float ee[4] = {e0, e1, e2, e3};
#pragma unroll
        for (int i = 0; i < 4; ++i) {
            const int rc = row0 + rg + i * 2;
            const int bb = rc >> 9, kk = rc & 511;
            EcT4[(((size_t)(bb * 32 + h4) * LK + kk) << 2) + hl] = ee[i];
        }
    }
}

// ---------------------------------------------------------------------------
// Attention: 1024 threads (16 waves), 4 q-rows/block, grid 512
// -> 2 blocks/CU = 32 waves/CU (full occupancy, 8 waves/SIMD).
// Phase 1 (score): k = t&511, hh = t>>9 splits H; Eq/Wv via SGPR s_loads;
//   paired rcp; partials to LDS.
// Phase 2 (softmax): waves 0-3 own rows; 1/sum folded in; output transposed
//   scT[k][4] so epilogue reads all 4 rows per k with one b128 broadcast.
// Phase 3 (epilogue): wave w: k-slice (w&7), d-half (w>>3); float2 ctx loads.
// Phase 4: combine 8 k-slices, store.
// LDS (aliased): scT [0,2048) | scpart [2048,6144) then part [2048,10240).
// ---------------------------------------------------------------------------
__global__ __launch_bounds__(1024, 8) void ca_attn_kernel(
    const float* __restrict__ Eq, const float* __restrict__ EcT4,
    const float* __restrict__ context, const float* __restrict__ Wv,
    float* __restrict__ out)
{
    __shared__ float smem[10240];   // 40 KB

    const int t = threadIdx.x;
    const int bq0 = blockIdx.x * 4;
    const int b = bq0 / LQ;

    const float4* __restrict__ ecb = (const float4*)EcT4 + (size_t)b * 32 * LK;
    const float* __restrict__ eqb = Eq + (size_t)bq0 * H;   // block-uniform

    // ---- phase 1: partial scores over this thread's H-half
    {
        const int k  = t & 511;
        const int hh = __builtin_amdgcn_readfirstlane(t >> 9); // 0/1, wave-uniform
        float a[4] = {0.f, 0.f, 0.f, 0.f};
        const int h4_0 = hh * 16;
#pragma unroll 2
        for (int i = 0; i < 16; ++i) {
            const int h4 = h4_0 + i;
            const float4 e = ecb[h4 * LK + k];                       // vector
            const float4 w = *(const float4*)(Wv + h4 * 4);          // s_load
#pragma unroll
            for (int g = 0; g < 4; ++g) {
                const float4 q = *(const float4*)(eqb + g * H + h4 * 4); // s_load
                const float A  = fmaf(q.x, e.x, 1.f);
                const float Bv = fmaf(q.y, e.y, 1.f);
                const float C  = fmaf(q.z, e.z, 1.f);
                const float D  = fmaf(q.w, e.w, 1.f);
                float n1 = w.x * Bv; n1 = fmaf(w.y, A, n1);
                float n2 = w.z * D;  n2 = fmaf(w.w, C, n2);
                const float r1 = __builtin_amdgcn_rcpf(A * Bv);
                const float r2 = __builtin_amdgcn_rcpf(C * D);
                a[g] = fmaf(n1, r1, a[g]);
                a[g] = fmaf(n2, r2, a[g]);
            }
        }
#pragma unroll
        for (int g = 0; g < 4; ++g)
            smem[2048 + hh * 2048 + g * 512 + k] = a[g];   // scpart
    }
    __syncthreads();

    // ---- phase 2: softmax (waves 0-3, wave g owns row g); fold 1/sum;
    //      write transposed scT[k][4]
    {
        const int w_id = t >> 6;
        const int lane = t & 63;
        if (w_id < 4) {
            float v[8];
#pragma unroll
            for (int i = 0; i < 8; ++i) {
                const int k = lane + 64 * i;
                const float p0 = smem[2048 + w_id * 512 + k];
                const float p1 = smem[4096 + w_id * 512 + k];
                v[i] = -2.f * (p0 + p1);
            }
            float m = v[0];
#pragma unroll
            for (int i = 1; i < 8; ++i) m = fmaxf(m, v[i]);
#pragma unroll
            for (int off = 32; off > 0; off >>= 1) m = fmaxf(m, __shfl_xor(m, off));
            float s = 0.f;
#pragma unroll
            for (int i = 0; i < 8; ++i) { v[i] = __expf(v[i] - m); s += v[i]; }
#pragma unroll
            for (int off = 32; off > 0; off >>= 1) s += __shfl_xor(s, off);
            const float r = 1.f / s;
#pragma unroll
            for (int i = 0; i < 8; ++i)
                smem[(lane + 64 * i) * 4 + w_id] = v[i] * r;   // scT
        }
    }
    __syncthreads();

    // ---- phase 3: epilogue partials. wave w: kh = w&7, dh = w>>3.
    {
        const int w_all = t >> 6;
        const int lane = t & 63;
        const int kh = __builtin_amdgcn_readfirstlane(w_all & 7);
        const int dh = __builtin_amdgcn_readfirstlane(w_all >> 3);
        const int d0 = dh * 128 + lane * 2;
        const float* __restrict__ ctx = context + (size_t)b * LK * DC + d0;
        float ox[4] = {0.f, 0.f, 0.f, 0.f};
        float oy[4] = {0.f, 0.f, 0.f, 0.f};
#pragma unroll 4
        for (int j = 0; j < 64; ++j) {
            const int k = kh * 64 + j;
            const float4 p = *(const float4*)&smem[k * 4];     // broadcast b128
            const float2 c = *(const float2*)(ctx + (size_t)k * DC);
            const float pl[4] = {p.x, p.y, p.z, p.w};
#pragma unroll
            for (int g = 0; g < 4; ++g) {
                ox[g] = fmaf(pl[g], c.x, ox[g]);
                oy[g] = fmaf(pl[g], c.y, oy[g]);
            }
        }
        const int base = 2048 + (((kh * 2 + dh) * 4) << 7) + lane * 2;
#pragma unroll
        for (int g = 0; g < 4; ++g) {
            smem[base + (g << 7) * 1 + 0] = ox[g];   // part[kh][dh][g][lane*2]
            smem[base + (g << 7) * 1 + 1] = oy[g];
        }
    }
    __syncthreads();

    // ---- phase 4: combine 8 k-slices, store
    {
        const int g = t >> 8;
        const int d = t & 255;
        const int dh = d >> 7, dl = d & 127;
        float s = 0.f;
#pragma unroll
        for (int kh = 0; kh < 8; ++kh)
            s += smem[2048 + (((kh * 2 + dh) * 4 + g) << 7) + dl];
        out[(size_t)(bq0 + g) * DC + d] = s;
    }
}

extern "C" void kernel_launch(void* const* d_in, const int* in_sizes, int n_in,
                              void* d_out, int out_size, void* d_ws, size_t ws_size,
                              hipStream_t stream) {
    const float* query   = (const float*)d_in[0];
    const float* context = (const float*)d_in[1];
    const float* Wq = (const float*)d_in[2];
    const float* bq = (const float*)d_in[3];
    const float* Wc = (const float*)d_in[4];
    const float* bc = (const float*)d_in[5];
    const float* Wv = (const float*)d_in[6];
    const float* bv = (const float*)d_in[7];  // dropped: softmax shift-invariant
    (void)bv;
    float* out = (float*)d_out;

    float* Eq   = (float*)d_ws;                     // 262144 floats
    float* EcT4 = Eq  + (size_t)B * LQ * H;         // 262144 floats
    float* WqT4 = EcT4 + (size_t)B * H * LK;        // 32768 floats
    float* WcT4 = WqT4 + (size_t)H * DQ;            // 32768 floats

    ca_wt_kernel<<<256, 256, 0, stream>>>(Wq, Wc, WqT4, WcT4);
    ca_proj_kernel<<<B * (LQ + LK) / 8, 256, 0, stream>>>(
        query, context, WqT4, WcT4, bq, bc, Eq, EcT4);
    ca_attn_kernel<<<B * LQ / 4, 1024, 0, stream>>>(Eq, EcT4, context, Wv, out);
}

// Round 6
// 110.276 us; speedup vs baseline: 1.0592x; 1.0592x over previous
//
#include <hip/hip_runtime.h>

#define B 4
#define LQ 512
#define LK 512
#define DQ 256
#define DC 256
#define H 128

// ws layout (floats):
//   Eq   [B*LQ][H]        = exp(2*(query@Wq^T + bq))            1 MB
//   EcT4 [B][H/4][LK][4]  = exp(4*(context@Wc^T + bc)), h-int.  1 MB
//   WqT4 [DQ/4][H][4]     transposed Wq                         128 KB
//   WcT4 [DC/4][H][4]     transposed Wc                         128 KB
//
// tanh(q + 2c) = 1 - 2/(e^{2q} e^{4c} + 1). The constant (bv + sum_h Wv)
// is softmax-shift-invariant and dropped. Paired reciprocals:
//   w0/A + w1/B = (w0*B + w1*A) / (A*B)  -> one rcp per two h.

__global__ __launch_bounds__(256) void ca_wt_kernel(
    const float* __restrict__ Wq, const float* __restrict__ Wc,
    float* __restrict__ WqT4, float* __restrict__ WcT4)
{
    const int blk = blockIdx.x;
    const bool is_q = blk < 128;
    const float* __restrict__ src = is_q ? Wq : Wc;
    float* __restrict__ dst = is_q ? WqT4 : WcT4;
    const int idx = ((is_q ? blk : blk - 128) << 8) + threadIdx.x; // h*DQ + d
    const int h = idx >> 8;
    const int d = idx & 255;
    dst[(((d >> 2) * H + h) << 2) + (d & 3)] = src[idx];
}

// ---------------------------------------------------------------------------
// Projection, LDS-free: 4 rows/block, 256 threads, grid 1024 (4 blocks/CU,
// 16 waves/CU = 4 waves/SIMD). h = t&127; rg = t>>7 wave-uniform
// (readfirstlane) -> x rows s_load'ed. Each thread: 2 rows (rg, rg+2) x 1 h.
// ---------------------------------------------------------------------------
__global__ __launch_bounds__(256, 4) void ca_proj_kernel(
    const float* __restrict__ query, const float* __restrict__ context,
    const float* __restrict__ WqT4, const float* __restrict__ WcT4,
    const float* __restrict__ bq, const float* __restrict__ bc,
    float* __restrict__ Eq, float* __restrict__ EcT4)
{
    const int t = threadIdx.x;
    const int blk = blockIdx.x;
    const bool is_q = blk < (B * LQ / 4);
    const int row0 = (is_q ? blk : blk - (B * LQ / 4)) * 4;
    const float* __restrict__ src = is_q ? query : context;
    const float4* __restrict__ w4 = (const float4*)(is_q ? WqT4 : WcT4);

    const int h = t & 127;
    const int rg = __builtin_amdgcn_readfirstlane(t >> 7); // wave-uniform 0/1

    const float* __restrict__ x0p = src + (size_t)(row0 + rg    ) * DQ;
    const float* __restrict__ x1p = src + (size_t)(row0 + rg + 2) * DQ;

    float acc0 = 0.f, acc1 = 0.f;
#pragma unroll 8
    for (int d4 = 0; d4 < DQ / 4; ++d4) {
        const float4 w  = w4[d4 * H + h];
        const float4 x0 = *(const float4*)(x0p + d4 * 4);
        const float4 x1 = *(const float4*)(x1p + d4 * 4);
        acc0 = fmaf(w.x, x0.x, acc0); acc0 = fmaf(w.y, x0.y, acc0);
        acc0 = fmaf(w.z, x0.z, acc0); acc0 = fmaf(w.w, x0.w, acc0);
        acc1 = fmaf(w.x, x1.x, acc1); acc1 = fmaf(w.y, x1.y, acc1);
        acc1 = fmaf(w.z, x1.z, acc1); acc1 = fmaf(w.w, x1.w, acc1);
    }

    const float bias = (is_q ? bq : bc)[h];
    if (is_q) {
        Eq[(size_t)(row0 + rg    ) * H + h] = __expf(2.f * (acc0 + bias));
        Eq[(size_t)(row0 + rg + 2) * H + h] = __expf(2.f * (acc1 + bias));
    } else {
        const int h4 = h >> 2, hl = h & 3;
        const float e0 = __expf(4.f * (acc0 + bias));
        const float e1 = __expf(4.f * (acc1 + bias));
        const int rc0 = row0 + rg, rc1 = row0 + rg + 2;
        EcT4[(((size_t)((rc0 >> 9) * 32 + h4) * LK + (rc0 & 511)) << 2) + hl] = e0;
        EcT4[(((size_t)((rc1 >> 9) * 32 + h4) * LK + (rc1 & 511)) << 2) + hl] = e1;
    }
}

// ---------------------------------------------------------------------------
// Attention: 512 threads (8 waves), 4 q-rows/block, grid 512.
// LDS pool = exactly 40 KB -> 4 blocks/CU (32 waves/CU); VGPR capped at 64
// via __launch_bounds__(512,8) (R4 measured 60).
// Aliasing: [0,2048) sc[4][512]; [2048,10240) part[8][4][256] (phase 3+),
// which also hosts eqs[4][128] @2048 and wv[128] @2560 during phase 1 only.
// Softmax folds 1/sum into p (no inv array needed).
// ---------------------------------------------------------------------------
__global__ __launch_bounds__(512, 8) void ca_attn_kernel(
    const float* __restrict__ Eq, const float* __restrict__ EcT4,
    const float* __restrict__ context, const float* __restrict__ Wv,
    float* __restrict__ out)
{
    __shared__ float smem[10240];   // 40 KB exactly
    float* __restrict__ sc   = smem;          // [4][512]
    float* __restrict__ eqs  = smem + 2048;   // [4][128]  (phase 1 only)
    float* __restrict__ wv   = smem + 2560;   // [128]     (phase 1 only)
    float* __restrict__ part = smem + 2048;   // [8][4][256] (phase 3+)

    const int t = threadIdx.x;
    const int bq0 = blockIdx.x * 4;
    const int b = bq0 / LQ;

    if (t < H) {
        wv[t] = Wv[t];
#pragma unroll
        for (int g = 0; g < 4; ++g) eqs[g * H + t] = Eq[(size_t)(bq0 + g) * H + t];
    }
    __syncthreads();

    const float4* __restrict__ ecb = (const float4*)EcT4 + (size_t)b * 32 * LK;

    // ---- phase 1: scores s[g][k=t] ~ -2 * sum_h Wv[h]/(Eq[g][h]*Ec[h][k]+1)
    {
        float a[4] = {0.f, 0.f, 0.f, 0.f};
#pragma unroll 4
        for (int h4 = 0; h4 < H / 4; ++h4) {
            const float4 e = ecb[h4 * LK + t];
            const float4 w = *(const float4*)&wv[h4 * 4];
#pragma unroll
            for (int g = 0; g < 4; ++g) {
                const float4 q = *(const float4*)&eqs[g * H + h4 * 4];
                const float A  = fmaf(q.x, e.x, 1.f);
                const float Bv = fmaf(q.y, e.y, 1.f);
                const float C  = fmaf(q.z, e.z, 1.f);
                const float D  = fmaf(q.w, e.w, 1.f);
                float n1 = w.x * Bv; n1 = fmaf(w.y, A, n1);
                float n2 = w.z * D;  n2 = fmaf(w.w, C, n2);
                const float r1 = __builtin_amdgcn_rcpf(A * Bv);
                const float r2 = __builtin_amdgcn_rcpf(C * D);
                a[g] = fmaf(n1, r1, a[g]);
                a[g] = fmaf(n2, r2, a[g]);
            }
        }
#pragma unroll
        for (int g = 0; g < 4; ++g) sc[g * 512 + t] = -2.f * a[g];
    }
    __syncthreads();

    // ---- phase 2: softmax; wave g (<4) owns row g; fold 1/sum into p
    {
        const int w_id = t >> 6;
        const int lane = t & 63;
        if (w_id < 4) {
            float v[8];
#pragma unroll
            for (int i = 0; i < 8; ++i) v[i] = sc[w_id * 512 + lane + 64 * i];
            float m = v[0];
#pragma unroll
            for (int i = 1; i < 8; ++i) m = fmaxf(m, v[i]);
#pragma unroll
            for (int off = 32; off > 0; off >>= 1) m = fmaxf(m, __shfl_xor(m, off));
            float s = 0.f;
#pragma unroll
            for (int i = 0; i < 8; ++i) { v[i] = __expf(v[i] - m); s += v[i]; }
#pragma unroll
            for (int off = 32; off > 0; off >>= 1) s += __shfl_xor(s, off);
            const float r = 1.f / s;
#pragma unroll
            for (int i = 0; i < 8; ++i) sc[w_id * 512 + lane + 64 * i] = v[i] * r;
        }
    }
    __syncthreads();

    // ---- phase 3: part[kh][g][d] = sum_{k in slice kh} p[g][k]*ctx[k][d]
    {
        const int kh = t >> 6;            // wave id = k-slice
        const int d4 = (t & 63) * 4;
        const float* __restrict__ ctx = context + (size_t)b * LK * DC + d4;
        float4 o[4];
#pragma unroll
        for (int g = 0; g < 4; ++g) o[g] = make_float4(0.f, 0.f, 0.f, 0.f);
#pragma unroll 2
        for (int j = 0; j < 16; ++j) {    // 4 k per iter
            const int k = kh * 64 + j * 4;
            float4 p[4];
#pragma unroll
            for (int g = 0; g < 4; ++g) p[g] = *(const float4*)&sc[g * 512 + k];
#pragma unroll
            for (int c = 0; c < 4; ++c) {
                const float4 cv = *(const float4*)(ctx + (size_t)(k + c) * DC);
                const float pc[4] = {p[0].x, p[1].x, p[2].x, p[3].x};
                const float pd[4] = {p[0].y, p[1].y, p[2].y, p[3].y};
                const float pe[4] = {p[0].z, p[1].z, p[2].z, p[3].z};
                const float pf[4] = {p[0].w, p[1].w, p[2].w, p[3].w};
                const float* sel = (c == 0) ? pc : (c == 1) ? pd : (c == 2) ? pe : pf;
#pragma unroll
                for (int g = 0; g < 4; ++g) {
                    o[g].x = fmaf(sel[g], cv.x, o[g].x);
                    o[g].y = fmaf(sel[g], cv.y, o[g].y);
                    o[g].z = fmaf(sel[g], cv.z, o[g].z);
                    o[g].w = fmaf(sel[g], cv.w, o[g].w);
                }
            }
        }
#pragma unroll
        for (int g = 0; g < 4; ++g)
            *(float4*)&part[kh * 1024 + g * 256 + d4] = o[g];
    }
    __syncthreads();

    // ---- phase 4: combine the 8 k-slices, store (1/sum already folded)
    if (t < 256) {
#pragma unroll
        for (int g = 0; g < 4; ++g) {
            float s = 0.f;
#pragma unroll
            for (int kh = 0; kh < 8; ++kh) s += part[kh * 1024 + g * 256 + t];
            out[(size_t)(bq0 + g) * DC + t] = s;
        }
    }
}

extern "C" void kernel_launch(void* const* d_in, const int* in_sizes, int n_in,
                              void* d_out, int out_size, void* d_ws, size_t ws_size,
                              hipStream_t stream) {
    const float* query   = (const float*)d_in[0];
    const float* context = (const float*)d_in[1];
    const float* Wq = (const float*)d_in[2];
    const float* bq = (const float*)d_in[3];
    const float* Wc = (const float*)d_in[4];
    const float* bc = (const float*)d_in[5];
    const float* Wv = (const float*)d_in[6];
    const float* bv = (const float*)d_in[7];  // dropped: softmax shift-invariant
    (void)bv;
    float* out = (float*)d_out;

    float* Eq   = (float*)d_ws;                     // 262144 floats
    float* EcT4 = Eq  + (size_t)B * LQ * H;         // 262144 floats
    float* WqT4 = EcT4 + (size_t)B * H * LK;        // 32768 floats
    float* WcT4 = WqT4 + (size_t)H * DQ;            // 32768 floats

    ca_wt_kernel<<<256, 256, 0, stream>>>(Wq, Wc, WqT4, WcT4);
    ca_proj_kernel<<<B * (LQ + LK) / 4, 256, 0, stream>>>(
        query, context, WqT4, WcT4, bq, bc, Eq, EcT4);
    ca_attn_kernel<<<B * LQ / 4, 512, 0, stream>>>(Eq, EcT4, context, Wv, out);
}

// Round 7
// 109.497 us; speedup vs baseline: 1.0668x; 1.0071x over previous
//
#include <hip/hip_runtime.h>

#define B 4
#define LQ 512
#define LK 512
#define DQ 256
#define DC 256
#define H 128

// ws layout (floats):
//   Eq   [B*LQ][H]        = exp(2*(query@Wq^T + bq))            1 MB
//   EcT4 [B][H/4][LK][4]  = exp(4*(context@Wc^T + bc)), h-int.  1 MB
//   WqT4 [DQ/4][H][4]     transposed Wq                         128 KB
//   WcT4 [DC/4][H][4]     transposed Wc                         128 KB
//
// tanh(q + 2c) = 1 - 2/(e^{2q} e^{4c} + 1). The constant (bv + sum_h Wv)
// is softmax-shift-invariant and dropped. 8-way paired reciprocals:
//   sum_{i=1..8} w_i/A_i = num / (A1..A8)  -> one rcp per EIGHT h.
//   Safe: prod(A_i) <= e^{sum 2|x_i|}, a 16-sigma event to overflow fp32.

__global__ __launch_bounds__(256) void ca_wt_kernel(
    const float* __restrict__ Wq, const float* __restrict__ Wc,
    float* __restrict__ WqT4, float* __restrict__ WcT4)
{
    const int blk = blockIdx.x;
    const bool is_q = blk < 128;
    const float* __restrict__ src = is_q ? Wq : Wc;
    float* __restrict__ dst = is_q ? WqT4 : WcT4;
    const int idx = ((is_q ? blk : blk - 128) << 8) + threadIdx.x; // h*DQ + d
    const int h = idx >> 8;
    const int d = idx & 255;
    dst[(((d >> 2) * H + h) << 2) + (d & 3)] = src[idx];
}

// ---------------------------------------------------------------------------
// Projection, LDS-free: 4 rows/block, 256 threads, grid 1024 (4 blocks/CU).
// h = t&127; rg = t>>7 wave-uniform (readfirstlane) -> x rows s_load'ed.
// Each thread: 2 rows (rg, rg+2) x 1 h.
// ---------------------------------------------------------------------------
__global__ __launch_bounds__(256, 4) void ca_proj_kernel(
    const float* __restrict__ query, const float* __restrict__ context,
    const float* __restrict__ WqT4, const float* __restrict__ WcT4,
    const float* __restrict__ bq, const float* __restrict__ bc,
    float* __restrict__ Eq, float* __restrict__ EcT4)
{
    const int t = threadIdx.x;
    const int blk = blockIdx.x;
    const bool is_q = blk < (B * LQ / 4);
    const int row0 = (is_q ? blk : blk - (B * LQ / 4)) * 4;
    const float* __restrict__ src = is_q ? query : context;
    const float4* __restrict__ w4 = (const float4*)(is_q ? WqT4 : WcT4);

    const int h = t & 127;
    const int rg = __builtin_amdgcn_readfirstlane(t >> 7); // wave-uniform 0/1

    const float* __restrict__ x0p = src + (size_t)(row0 + rg    ) * DQ;
    const float* __restrict__ x1p = src + (size_t)(row0 + rg + 2) * DQ;

    float acc0 = 0.f, acc1 = 0.f;
#pragma unroll 8
    for (int d4 = 0; d4 < DQ / 4; ++d4) {
        const float4 w  = w4[d4 * H + h];
        const float4 x0 = *(const float4*)(x0p + d4 * 4);
        const float4 x1 = *(const float4*)(x1p + d4 * 4);
        acc0 = fmaf(w.x, x0.x, acc0); acc0 = fmaf(w.y, x0.y, acc0);
        acc0 = fmaf(w.z, x0.z, acc0); acc0 = fmaf(w.w, x0.w, acc0);
        acc1 = fmaf(w.x, x1.x, acc1); acc1 = fmaf(w.y, x1.y, acc1);
        acc1 = fmaf(w.z, x1.z, acc1); acc1 = fmaf(w.w, x1.w, acc1);
    }

    const float bias = (is_q ? bq : bc)[h];
    if (is_q) {
        Eq[(size_t)(row0 + rg    ) * H + h] = __expf(2.f * (acc0 + bias));
        Eq[(size_t)(row0 + rg + 2) * H + h] = __expf(2.f * (acc1 + bias));
    } else {
        const int h4 = h >> 2, hl = h & 3;
        const float e0 = __expf(4.f * (acc0 + bias));
        const float e1 = __expf(4.f * (acc1 + bias));
        const int rc0 = row0 + rg, rc1 = row0 + rg + 2;
        EcT4[(((size_t)((rc0 >> 9) * 32 + h4) * LK + (rc0 & 511)) << 2) + hl] = e0;
        EcT4[(((size_t)((rc1 >> 9) * 32 + h4) * LK + (rc1 & 511)) << 2) + hl] = e1;
    }
}

// ---------------------------------------------------------------------------
// Attention: 512 threads (8 waves), 4 q-rows/block, grid 512.
// LDS pool = exactly 40 KB -> 4 blocks/CU; VGPR capped via (512,8).
// Aliasing: [0,2048) sc[4][512]; [2048,10240) part[8][4][256] (phase 3+),
// hosting eqs[4][128] @2048 and wv[128] @2560 during phase 1 only.
// Phase 1 uses 8-way paired reciprocals: 30 VALU + 1 rcp per (g, 8h).
// ---------------------------------------------------------------------------
__global__ __launch_bounds__(512, 8) void ca_attn_kernel(
    const float* __restrict__ Eq, const float* __restrict__ EcT4,
    const float* __restrict__ context, const float* __restrict__ Wv,
    float* __restrict__ out)
{
    __shared__ float smem[10240];   // 40 KB exactly
    float* __restrict__ sc   = smem;          // [4][512]
    float* __restrict__ eqs  = smem + 2048;   // [4][128]  (phase 1 only)
    float* __restrict__ wv   = smem + 2560;   // [128]     (phase 1 only)
    float* __restrict__ part = smem + 2048;   // [8][4][256] (phase 3+)

    const int t = threadIdx.x;
    const int bq0 = blockIdx.x * 4;
    const int b = bq0 / LQ;

    if (t < H) {
        wv[t] = Wv[t];
#pragma unroll
        for (int g = 0; g < 4; ++g) eqs[g * H + t] = Eq[(size_t)(bq0 + g) * H + t];
    }
    __syncthreads();

    const float4* __restrict__ ecb = (const float4*)EcT4 + (size_t)b * 32 * LK;

    // ---- phase 1: scores s[g][k=t] ~ -2 * sum_h Wv[h]/(Eq[g][h]*Ec[h][k]+1)
    {
        float a[4] = {0.f, 0.f, 0.f, 0.f};
#pragma unroll 2
        for (int h8 = 0; h8 < H / 8; ++h8) {
            const float4 e1 = ecb[(2 * h8    ) * LK + t];
            const float4 e2 = ecb[(2 * h8 + 1) * LK + t];
            const float4 w1 = *(const float4*)&wv[h8 * 8];
            const float4 w2 = *(const float4*)&wv[h8 * 8 + 4];
#pragma unroll
            for (int g = 0; g < 4; ++g) {
                const float4 q1 = *(const float4*)&eqs[g * H + h8 * 8];
                const float4 q2 = *(const float4*)&eqs[g * H + h8 * 8 + 4];
                const float A1 = fmaf(q1.x, e1.x, 1.f);
                const float B1 = fmaf(q1.y, e1.y, 1.f);
                const float C1 = fmaf(q1.z, e1.z, 1.f);
                const float D1 = fmaf(q1.w, e1.w, 1.f);
                const float A2 = fmaf(q2.x, e2.x, 1.f);
                const float B2 = fmaf(q2.y, e2.y, 1.f);
                const float C2 = fmaf(q2.z, e2.z, 1.f);
                const float D2 = fmaf(q2.w, e2.w, 1.f);
                const float P1a = A1 * B1, P1b = C1 * D1;
                const float P2a = A2 * B2, P2b = C2 * D2;
                const float P1 = P1a * P1b, P2 = P2a * P2b;
                float n1a = w1.x * B1; n1a = fmaf(w1.y, A1, n1a);
                float n1b = w1.z * D1; n1b = fmaf(w1.w, C1, n1b);
                float num1 = n1a * P1b; num1 = fmaf(n1b, P1a, num1);
                float n2a = w2.x * B2; n2a = fmaf(w2.y, A2, n2a);
                float n2b = w2.z * D2; n2b = fmaf(w2.w, C2, n2b);
                float num2 = n2a * P2b; num2 = fmaf(n2b, P2a, num2);
                float num = num1 * P2; num = fmaf(num2, P1, num);
                const float r = __builtin_amdgcn_rcpf(P1 * P2);
                a[g] = fmaf(num, r, a[g]);
            }
        }
#pragma unroll
        for (int g = 0; g < 4; ++g) sc[g * 512 + t] = -2.f * a[g];
    }
    __syncthreads();

    // ---- phase 2: softmax; wave g (<4) owns row g; fold 1/sum into p
    {
        const int w_id = t >> 6;
        const int lane = t & 63;
        if (w_id < 4) {
            float v[8];
#pragma unroll
            for (int i = 0; i < 8; ++i) v[i] = sc[w_id * 512 + lane + 64 * i];
            float m = v[0];
#pragma unroll
            for (int i = 1; i < 8; ++i) m = fmaxf(m, v[i]);
#pragma unroll
            for (int off = 32; off > 0; off >>= 1) m = fmaxf(m, __shfl_xor(m, off));
            float s = 0.f;
#pragma unroll
            for (int i = 0; i < 8; ++i) { v[i] = __expf(v[i] - m); s += v[i]; }
#pragma unroll
            for (int off = 32; off > 0; off >>= 1) s += __shfl_xor(s, off);
            const float r = 1.f / s;
#pragma unroll
            for (int i = 0; i < 8; ++i) sc[w_id * 512 + lane + 64 * i] = v[i] * r;
        }
    }
    __syncthreads();

    // ---- phase 3: part[kh][g][d] = sum_{k in slice kh} p[g][k]*ctx[k][d]
    {
        const int kh = t >> 6;            // wave id = k-slice
        const int d4 = (t & 63) * 4;
        const float* __restrict__ ctx = context + (size_t)b * LK * DC + d4;
        float4 o[4];
#pragma unroll
        for (int g = 0; g < 4; ++g) o[g] = make_float4(0.f, 0.f, 0.f, 0.f);
#pragma unroll 2
        for (int j = 0; j < 16; ++j) {    // 4 k per iter
            const int k = kh * 64 + j * 4;
            float4 p[4];
#pragma unroll
            for (int g = 0; g < 4; ++g) p[g] = *(const float4*)&sc[g * 512 + k];
#pragma unroll
            for (int c = 0; c < 4; ++c) {
                const float4 cv = *(const float4*)(ctx + (size_t)(k + c) * DC);
                const float pc[4] = {p[0].x, p[1].x, p[2].x, p[3].x};
                const float pd[4] = {p[0].y, p[1].y, p[2].y, p[3].y};
                const float pe[4] = {p[0].z, p[1].z, p[2].z, p[3].z};
                const float pf[4] = {p[0].w, p[1].w, p[2].w, p[3].w};
                const float* sel = (c == 0) ? pc : (c == 1) ? pd : (c == 2) ? pe : pf;
#pragma unroll
                for (int g = 0; g < 4; ++g) {
                    o[g].x = fmaf(sel[g], cv.x, o[g].x);
                    o[g].y = fmaf(sel[g], cv.y, o[g].y);
                    o[g].z = fmaf(sel[g], cv.z, o[g].z);
                    o[g].w = fmaf(sel[g], cv.w, o[g].w);
                }
            }
        }
#pragma unroll
        for (int g = 0; g < 4; ++g)
            *(float4*)&part[kh * 1024 + g * 256 + d4] = o[g];
    }
    __syncthreads();

    // ---- phase 4: combine the 8 k-slices, store (1/sum already folded)
    if (t < 256) {
#pragma unroll
        for (int g = 0; g < 4; ++g) {
            float s = 0.f;
#pragma unroll
            for (int kh = 0; kh < 8; ++kh) s += part[kh * 1024 + g * 256 + t];
            out[(size_t)(bq0 + g) * DC + t] = s;
        }
    }
}

extern "C" void kernel_launch(void* const* d_in, const int* in_sizes, int n_in,
                              void* d_out, int out_size, void* d_ws, size_t ws_size,
                              hipStream_t stream) {
    const float* query   = (const float*)d_in[0];
    const float* context = (const float*)d_in[1];
    const float* Wq = (const float*)d_in[2];
    const float* bq = (const float*)d_in[3];
    const float* Wc = (const float*)d_in[4];
    const float* bc = (const float*)d_in[5];
    const float* Wv = (const float*)d_in[6];
    const float* bv = (const float*)d_in[7];  // dropped: softmax shift-invariant
    (void)bv;
    float* out = (float*)d_out;

    float* Eq   = (float*)d_ws;                     // 262144 floats
    float* EcT4 = Eq  + (size_t)B * LQ * H;         // 262144 floats
    float* WqT4 = EcT4 + (size_t)B * H * LK;        // 32768 floats
    float* WcT4 = WqT4 + (size_t)H * DQ;            // 32768 floats

    ca_wt_kernel<<<256, 256, 0, stream>>>(Wq, Wc, WqT4, WcT4);
    ca_proj_kernel<<<B * (LQ + LK) / 4, 256, 0, stream>>>(
        query, context, WqT4, WcT4, bq, bc, Eq, EcT4);
    ca_attn_kernel<<<B * LQ / 4, 512, 0, stream>>>(Eq, EcT4, context, Wv, out);
}